// Round 1
// baseline (259.345 us; speedup 1.0000x reference)
//
#include <hip/hip_runtime.h>
#include <cmath>

#define B_   128
#define H_   256
#define W_   256
#define WC_  129
#define L_   182
#define PI_F 3.14159265358979f

// ---------------------------------------------------------------------------
// Wave-synchronous 256-point DIF FFT across one 64-lane wave.
// Lane l holds 4 complex elements in registers: slot j = x[l + 64*j].
// Output: storage index q = l + 64*j holds X[bitrev8(q)].
// ---------------------------------------------------------------------------
__device__ __forceinline__ void fft256_wave(float vr[4], float vi[4], int l) {
  float c0, s0;
  __sincosf(-2.f * PI_F * (float)l / 256.f, &s0, &c0);  // w0 = W256^l
  {
    float ur = vr[0] + vr[2], ui = vi[0] + vi[2];
    float dr = vr[0] - vr[2], di = vi[0] - vi[2];
    vr[0] = ur; vi[0] = ui;
    vr[2] = dr * c0 - di * s0; vi[2] = dr * s0 + di * c0;
    float c1 = s0, s1 = -c0;
    ur = vr[1] + vr[3]; ui = vi[1] + vi[3];
    dr = vr[1] - vr[3]; di = vi[1] - vi[3];
    vr[1] = ur; vi[1] = ui;
    vr[3] = dr * c1 - di * s1; vi[3] = dr * s1 + di * c1;
  }
  {
    float c2 = c0 * c0 - s0 * s0, s2 = 2.f * c0 * s0;
    float ur = vr[0] + vr[1], ui = vi[0] + vi[1];
    float dr = vr[0] - vr[1], di = vi[0] - vi[1];
    vr[0] = ur; vi[0] = ui;
    vr[1] = dr * c2 - di * s2; vi[1] = dr * s2 + di * c2;
    ur = vr[2] + vr[3]; ui = vi[2] + vi[3];
    dr = vr[2] - vr[3]; di = vi[2] - vi[3];
    vr[2] = ur; vi[2] = ui;
    vr[3] = dr * c2 - di * s2; vi[3] = dr * s2 + di * c2;
  }
  #pragma unroll
  for (int h = 32; h >= 1; h >>= 1) {
    int i = l & (h - 1);
    float c, s;
    __sincosf(-PI_F * (float)i / (float)h, &s, &c);
    bool up = (l & h) != 0;
    float cc = up ? c : 1.f;
    float ss = up ? s : 0.f;
    float sgn = up ? -1.f : 1.f;
    #pragma unroll
    for (int j = 0; j < 4; ++j) {
      float br = __shfl_xor(vr[j], h, 64);
      float bi = __shfl_xor(vi[j], h, 64);
      float tr = fmaf(sgn, vr[j], br);
      float ti = fmaf(sgn, vi[j], bi);
      vr[j] = tr * cc - ti * ss;
      vi[j] = tr * ss + ti * cc;
    }
  }
}

#define P1_PAIRS 16
#define P1_STRIDE 259  // float2 LDS stride breaks pow2 bank pattern

// Pass 1: luma + row FFT (two-real-rows-in-one-complex-FFT trick), writes
// inter[b][k][row]. Extra block (blockIdx == B_*8) computes the radial
// count histogram once (batch-independent), hidden under the other blocks.
__global__ __launch_bounds__(1024) void pass1_kernel(
    const float* __restrict__ data, float4* __restrict__ inter4,
    const int* __restrict__ radius, float* __restrict__ cnt) {
  __shared__ float2 tile[P1_PAIRS * P1_STRIDE];
  int tid = threadIdx.x;
  if (blockIdx.x == B_ * 8) {
    // counts block: histogram of radius[] into LDS, then one global write.
    float* lcnt = (float*)tile;  // alias pass1's tile storage
    for (int i = tid; i < L_; i += 1024) lcnt[i] = 0.f;
    __syncthreads();
    for (int i = tid; i < H_ * WC_; i += 1024)
      atomicAdd(&lcnt[radius[i]], 1.f);
    __syncthreads();
    for (int i = tid; i < L_; i += 1024) cnt[i] = lcnt[i];
    return;
  }
  int w = tid >> 6, l = tid & 63;
  int b = blockIdx.x >> 3;
  int row0 = (blockIdx.x & 7) * 32;
  int rowA = row0 + 2 * w;
  const float* pA = data + ((size_t)b * 3) * (H_ * W_) + (size_t)rowA * W_;
  float vr[4], vi[4];
  #pragma unroll
  for (int j = 0; j < 4; ++j) {
    int i = l + 64 * j;
    float r = pA[i], g = pA[H_ * W_ + i], bl = pA[2 * H_ * W_ + i];
    vr[j] = fmaf(0.299f, r, fmaf(0.587f, g, 0.114f * bl));
    r = pA[W_ + i]; g = pA[H_ * W_ + W_ + i]; bl = pA[2 * H_ * W_ + W_ + i];
    vi[j] = fmaf(0.299f, r, fmaf(0.587f, g, 0.114f * bl));
  }
  fft256_wave(vr, vi, l);
  #pragma unroll
  for (int j = 0; j < 4; ++j)
    tile[w * P1_STRIDE + l + 64 * j] = make_float2(vr[j], vi[j]);
  __syncthreads();
  // X(k) sits at storage q = bitrev8(k). Unpack via conjugate symmetry:
  //   A(k) = (Z(k)+conj(Z(N-k)))/2 ; B(k) = (Z(k)-conj(Z(N-k)))/(2i)
  for (int f = tid; f < WC_ * P1_PAIRS; f += 1024) {
    int k = f >> 4;
    int p = f & 15;
    int qk  = (int)(__brev((unsigned)k) >> 24);
    int qnk = (int)(__brev((unsigned)((256 - k) & 255)) >> 24);
    float2 Zk  = tile[p * P1_STRIDE + qk];
    float2 Znk = tile[p * P1_STRIDE + qnk];
    float4 o;
    o.x = 0.5f * (Zk.x + Znk.x);   // A.re
    o.y = 0.5f * (Zk.y - Znk.y);   // A.im
    o.z = 0.5f * (Zk.y + Znk.y);   // B.re
    o.w = 0.5f * (Znk.x - Zk.x);   // B.im
    inter4[((((size_t)b * WC_ + k) * H_ + row0) >> 1) + p] = o;
  }
}

// Pass 2 (fused): one block per image. 16 waves sweep all 129 columns
// (9 rounds), column FFT + log-power + radial binning into ONE LDS bin
// array. Then wave 0 finishes: segment mean, min-max normalize, L1 vs
// mean profile — entirely in-register via shfl reductions. No partials,
// no separate loss kernel.
__global__ __launch_bounds__(1024) void pass2_fused(
    const float2* __restrict__ inter, const int* __restrict__ radius,
    const float* __restrict__ cnt, const float* __restrict__ mean,
    float* __restrict__ lpart) {
  __shared__ float lbins[L_];
  int tid = threadIdx.x;
  int wv = tid >> 6, l = tid & 63;
  int b = blockIdx.x;
  for (int i = tid; i < L_; i += 1024) lbins[i] = 0.f;
  __syncthreads();
  #pragma unroll 1
  for (int round = 0; round < 9; ++round) {
    int k = round * 16 + wv;
    if (k < WC_) {
      const float2* p = inter + ((size_t)b * WC_ + k) * H_;
      float vr[4], vi[4];
      #pragma unroll
      for (int j = 0; j < 4; ++j) {
        float2 v = p[l + 64 * j];
        vr[j] = v.x; vi[j] = v.y;
      }
      fft256_wave(vr, vi, l);
      int rb = 4 * (int)(__brev((unsigned)l) >> 26);
      #pragma unroll
      for (int j = 0; j < 4; ++j) {
        int rf = rb + ((j == 1) ? 2 : (j == 2) ? 1 : j);  // bitrev2(j)
        int bin = radius[rf * WC_ + k];
        float pw = vr[j] * vr[j] + vi[j] * vi[j];
        float val = 20.f * __logf(pw + 1e-8f);
        atomicAdd(&lbins[bin], val);
      }
    }
  }
  __syncthreads();
  if (wv == 0) {
    // lanes cover bins {l, l+64, l+128(<182)}
    float pa = lbins[l] / cnt[l];
    float pb = lbins[l + 64] / cnt[l + 64];
    bool v2 = (l + 128) < L_;
    float pc = v2 ? lbins[l + 128] / cnt[l + 128] : 0.f;
    float mn = fminf(pa, pb);
    if (v2) mn = fminf(mn, pc);
    #pragma unroll
    for (int h = 32; h >= 1; h >>= 1) mn = fminf(mn, __shfl_xor(mn, h, 64));
    float mxr = fmaxf(pa, pb);
    if (v2) mxr = fmaxf(mxr, pc);
    #pragma unroll
    for (int h = 32; h >= 1; h >>= 1) mxr = fmaxf(mxr, __shfl_xor(mxr, h, 64));
    float mx = mxr - mn;  // == max(profile - mn): max attained at same element
    float s = fabsf((pa - mn) / mx - mean[l]) +
              fabsf((pb - mn) / mx - mean[l + 64]);
    if (v2) s += fabsf((pc - mn) / mx - mean[l + 128]);
    #pragma unroll
    for (int h = 32; h >= 1; h >>= 1) s += __shfl_xor(s, h, 64);
    if (l == 0) lpart[b] = s;
  }
}

// Final: one wave sums the 128 per-sample losses, plain store to out.
__global__ __launch_bounds__(64) void final_kernel(
    const float* __restrict__ lpart, float* __restrict__ out) {
  int l = threadIdx.x;
  float v = lpart[l] + lpart[l + 64];
  #pragma unroll
  for (int h = 32; h >= 1; h >>= 1) v += __shfl_xor(v, h, 64);
  if (l == 0) out[0] = v;
}

extern "C" void kernel_launch(void* const* d_in, const int* in_sizes, int n_in,
                              void* d_out, int out_size, void* d_ws, size_t ws_size,
                              hipStream_t stream) {
  const float* data   = (const float*)d_in[0];  // [128,3,256,256] f32
  const float* mean   = (const float*)d_in[1];  // [182] f32
  const int*   radius = (const int*)d_in[2];    // [256,129] i32
  float* out = (float*)d_out;                   // scalar f32

  float2* inter = (float2*)d_ws;                           // [B][WC][H] complex
  size_t inter_bytes = (size_t)B_ * WC_ * H_ * sizeof(float2);
  float* cnt   = (float*)((char*)d_ws + inter_bytes);      // [L] (padded to 256)
  float* lpart = cnt + 256;                                // [B]

  pass1_kernel<<<B_ * 8 + 1, 1024, 0, stream>>>(data, (float4*)inter, radius, cnt);
  pass2_fused<<<B_, 1024, 0, stream>>>(inter, radius, cnt, mean, lpart);
  final_kernel<<<1, 64, 0, stream>>>(lpart, out);
}

// Round 2
// 202.424 us; speedup vs baseline: 1.2812x; 1.2812x over previous
//
#include <hip/hip_runtime.h>
#include <cmath>

#define B_   128
#define H_   256
#define W_   256
#define WC_  129
#define L_   182
#define NG_  17    // column groups per image in pass2 (8 cols/group * 17 >= 129)
#define PI_F 3.14159265358979f

// ---------------------------------------------------------------------------
// Two interleaved wave-synchronous 256-point DIF FFTs across one 64-lane wave.
// FFT A in slots 0..3, FFT B in slots 4..7; slot j holds x[l + 64*(j&3)].
// Twiddles are shared (same lane index) -> half the sincos work, and the two
// independent shfl chains interleave to hide DS latency (kernels were
// latency-bound: VALUBusy 10%, HBM 12%).
// Output: storage q = l + 64*(j&3) holds X[bitrev8(q)] of the respective FFT.
// ---------------------------------------------------------------------------
__device__ __forceinline__ void fft256x2_wave(float vr[8], float vi[8], int l) {
  float c0, s0;
  __sincosf(-2.f * PI_F * (float)l / 256.f, &s0, &c0);  // W256^l
  float c1 = s0, s1 = -c0;                              // W256^(l+64)
  float c2 = c0 * c0 - s0 * s0, s2 = 2.f * c0 * s0;     // W128^l
  #pragma unroll
  for (int f = 0; f < 8; f += 4) {
    // distance-128 butterflies
    float ur = vr[f+0] + vr[f+2], ui = vi[f+0] + vi[f+2];
    float dr = vr[f+0] - vr[f+2], di = vi[f+0] - vi[f+2];
    vr[f+0] = ur; vi[f+0] = ui;
    vr[f+2] = dr * c0 - di * s0; vi[f+2] = dr * s0 + di * c0;
    ur = vr[f+1] + vr[f+3]; ui = vi[f+1] + vi[f+3];
    dr = vr[f+1] - vr[f+3]; di = vi[f+1] - vi[f+3];
    vr[f+1] = ur; vi[f+1] = ui;
    vr[f+3] = dr * c1 - di * s1; vi[f+3] = dr * s1 + di * c1;
    // distance-64 butterflies
    ur = vr[f+0] + vr[f+1]; ui = vi[f+0] + vi[f+1];
    dr = vr[f+0] - vr[f+1]; di = vi[f+0] - vi[f+1];
    vr[f+0] = ur; vi[f+0] = ui;
    vr[f+1] = dr * c2 - di * s2; vi[f+1] = dr * s2 + di * c2;
    ur = vr[f+2] + vr[f+3]; ui = vi[f+2] + vi[f+3];
    dr = vr[f+2] - vr[f+3]; di = vi[f+2] - vi[f+3];
    vr[f+2] = ur; vi[f+2] = ui;
    vr[f+3] = dr * c2 - di * s2; vi[f+3] = dr * s2 + di * c2;
  }
  #pragma unroll
  for (int h = 32; h >= 1; h >>= 1) {
    int i = l & (h - 1);
    float c, s;
    __sincosf(-PI_F * (float)i / (float)h, &s, &c);
    bool up = (l & h) != 0;
    float cc = up ? c : 1.f;
    float ss = up ? s : 0.f;
    float sgn = up ? -1.f : 1.f;
    #pragma unroll
    for (int j = 0; j < 8; ++j) {
      float br = __shfl_xor(vr[j], h, 64);
      float bi = __shfl_xor(vi[j], h, 64);
      float tr = fmaf(sgn, vr[j], br);
      float ti = fmaf(sgn, vi[j], bi);
      vr[j] = tr * cc - ti * ss;
      vi[j] = tr * ss + ti * cc;
    }
  }
}

#define P1_PAIRS 8
#define P1_STRIDE 259  // float2 LDS stride breaks pow2 bank pattern

// Pass 1: luma + row FFT (two-real-rows-in-one-complex-FFT trick). 256-thr
// blocks, 4 waves x 2 FFTs = 8 row-pairs (16 rows) per block. Grid = 2048
// blocks = exactly 8 blocks/CU across 256 CUs -> single dispatch round.
__global__ __launch_bounds__(256) void pass1_kernel(
    const float* __restrict__ data, float4* __restrict__ inter4) {
  __shared__ float2 tile[P1_PAIRS * P1_STRIDE];
  int tid = threadIdx.x;
  int w = tid >> 6, l = tid & 63;
  int b = blockIdx.x >> 4;
  int row0 = (blockIdx.x & 15) * 16;
  const float* base = data + (size_t)b * 3 * (H_ * W_);
  float vr[8], vi[8];
  #pragma unroll
  for (int f = 0; f < 2; ++f) {
    int rowA = row0 + 2 * w + 8 * f;   // pair p = w + 4*f
    const float* pR = base + (size_t)rowA * W_;
    #pragma unroll
    for (int j = 0; j < 4; ++j) {
      int i = l + 64 * j;
      float r = pR[i], g = pR[H_ * W_ + i], bl = pR[2 * H_ * W_ + i];
      vr[4 * f + j] = fmaf(0.299f, r, fmaf(0.587f, g, 0.114f * bl));
      r = pR[W_ + i]; g = pR[H_ * W_ + W_ + i]; bl = pR[2 * H_ * W_ + W_ + i];
      vi[4 * f + j] = fmaf(0.299f, r, fmaf(0.587f, g, 0.114f * bl));
    }
  }
  fft256x2_wave(vr, vi, l);
  #pragma unroll
  for (int j = 0; j < 4; ++j) {
    tile[w * P1_STRIDE + l + 64 * j]       = make_float2(vr[j],     vi[j]);
    tile[(w + 4) * P1_STRIDE + l + 64 * j] = make_float2(vr[4 + j], vi[4 + j]);
  }
  __syncthreads();
  // X(k) sits at storage q = bitrev8(k). Unpack via conjugate symmetry:
  //   A(k) = (Z(k)+conj(Z(N-k)))/2 ; B(k) = (Z(k)-conj(Z(N-k)))/(2i)
  for (int f = tid; f < WC_ * P1_PAIRS; f += 256) {
    int k = f >> 3;
    int p = f & 7;
    int qk  = (int)(__brev((unsigned)k) >> 24);
    int qnk = (int)(__brev((unsigned)((256 - k) & 255)) >> 24);
    float2 Zk  = tile[p * P1_STRIDE + qk];
    float2 Znk = tile[p * P1_STRIDE + qnk];
    float4 o;
    o.x = 0.5f * (Zk.x + Znk.x);   // A.re
    o.y = 0.5f * (Zk.y - Znk.y);   // A.im
    o.z = 0.5f * (Zk.y + Znk.y);   // B.re
    o.w = 0.5f * (Znk.x - Zk.x);   // B.im
    inter4[((((size_t)b * WC_ + k) * H_ + row0) >> 1) + p] = o;
  }
}

// Pass 2: column FFT + log-power + radial binning into per-block LDS bins,
// flushed to partial[b][g][L]. 4 waves x 2 FFTs = 8 columns per block.
// Blocks with b==0 also histogram the radial counts for their 8 columns
// (batch-independent) into cntpart[g][L] -- distributed, no serial tail.
__global__ __launch_bounds__(256) void pass2_kernel(
    const float2* __restrict__ inter, const int* __restrict__ radius,
    float* __restrict__ partial, float* __restrict__ cntpart) {
  __shared__ float lbins[L_];
  __shared__ float lcnt[L_];
  int tid = threadIdx.x;
  int wv = tid >> 6, l = tid & 63;
  int b = blockIdx.x / NG_;
  int g = blockIdx.x - b * NG_;
  int k1 = g * 8 + wv;
  int k2 = k1 + 4;
  bool v1 = k1 < WC_, v2 = k2 < WC_;
  bool do_cnt = (b == 0);
  for (int i = tid; i < L_; i += 256) lbins[i] = 0.f;
  if (do_cnt)
    for (int i = tid; i < L_; i += 256) lcnt[i] = 0.f;
  __syncthreads();
  float vr[8], vi[8];
  const float2* p1 = inter + ((size_t)b * WC_ + k1) * H_;
  const float2* p2 = inter + ((size_t)b * WC_ + k2) * H_;
  #pragma unroll
  for (int j = 0; j < 4; ++j) {
    float2 a = v1 ? p1[l + 64 * j] : make_float2(0.f, 0.f);
    float2 c = v2 ? p2[l + 64 * j] : make_float2(0.f, 0.f);
    vr[j] = a.x; vi[j] = a.y;
    vr[4 + j] = c.x; vi[4 + j] = c.y;
  }
  fft256x2_wave(vr, vi, l);
  int rb = 4 * (int)(__brev((unsigned)l) >> 26);
  #pragma unroll
  for (int j = 0; j < 4; ++j) {
    int rf = rb + ((j == 1) ? 2 : (j == 2) ? 1 : j);  // bitrev2(j)
    if (v1) {
      int bin = radius[rf * WC_ + k1];
      float pw = vr[j] * vr[j] + vi[j] * vi[j];
      atomicAdd(&lbins[bin], 20.f * __logf(pw + 1e-8f));
      if (do_cnt) atomicAdd(&lcnt[bin], 1.f);
    }
    if (v2) {
      int bin = radius[rf * WC_ + k2];
      float pw = vr[4 + j] * vr[4 + j] + vi[4 + j] * vi[4 + j];
      atomicAdd(&lbins[bin], 20.f * __logf(pw + 1e-8f));
      if (do_cnt) atomicAdd(&lcnt[bin], 1.f);
    }
  }
  __syncthreads();
  float* pp = partial + ((size_t)b * NG_ + g) * L_;
  for (int i = tid; i < L_; i += 256) pp[i] = lbins[i];
  if (do_cnt) {
    float* cp = cntpart + (size_t)g * L_;
    for (int i = tid; i < L_; i += 256) cp[i] = lcnt[i];
  }
}

// One wave per batch sample: reduce 17 value+count partials, segment mean,
// min-max normalize, L1 vs mean — all in-register via shfl (no barrier trees).
__global__ __launch_bounds__(64) void loss_kernel(
    const float* __restrict__ partial, const float* __restrict__ cntpart,
    const float* __restrict__ mean, float* __restrict__ lpart) {
  int b = blockIdx.x;
  int l = threadIdx.x;
  const float* pb = partial + (size_t)b * NG_ * L_;
  float s0 = 0.f, s1 = 0.f, s2 = 0.f;
  float n0 = 0.f, n1 = 0.f, n2 = 0.f;
  #pragma unroll 1
  for (int g = 0; g < NG_; ++g) {
    s0 += pb[g * L_ + l];        n0 += cntpart[g * L_ + l];
    s1 += pb[g * L_ + l + 64];   n1 += cntpart[g * L_ + l + 64];
  }
  bool has2 = (l + 128) < L_;
  if (has2) {
    #pragma unroll 1
    for (int g = 0; g < NG_; ++g) {
      s2 += pb[g * L_ + l + 128];
      n2 += cntpart[g * L_ + l + 128];
    }
  }
  float pa = s0 / n0;
  float pc = s1 / n1;
  float pe = has2 ? (s2 / n2) : 0.f;
  float mn = fminf(pa, pc);
  if (has2) mn = fminf(mn, pe);
  #pragma unroll
  for (int h = 32; h >= 1; h >>= 1) mn = fminf(mn, __shfl_xor(mn, h, 64));
  float mxr = fmaxf(pa, pc);
  if (has2) mxr = fmaxf(mxr, pe);
  #pragma unroll
  for (int h = 32; h >= 1; h >>= 1) mxr = fmaxf(mxr, __shfl_xor(mxr, h, 64));
  float mx = mxr - mn;  // max(profile - mn): max attained at the same element
  float s = fabsf((pa - mn) / mx - mean[l]) +
            fabsf((pc - mn) / mx - mean[l + 64]);
  if (has2) s += fabsf((pe - mn) / mx - mean[l + 128]);
  #pragma unroll
  for (int h = 32; h >= 1; h >>= 1) s += __shfl_xor(s, h, 64);
  if (l == 0) lpart[b] = s;
}

// Final: one wave sums the 128 per-sample losses, plain store to out.
__global__ __launch_bounds__(64) void final_kernel(
    const float* __restrict__ lpart, float* __restrict__ out) {
  int l = threadIdx.x;
  float v = lpart[l] + lpart[l + 64];
  #pragma unroll
  for (int h = 32; h >= 1; h >>= 1) v += __shfl_xor(v, h, 64);
  if (l == 0) out[0] = v;
}

extern "C" void kernel_launch(void* const* d_in, const int* in_sizes, int n_in,
                              void* d_out, int out_size, void* d_ws, size_t ws_size,
                              hipStream_t stream) {
  const float* data   = (const float*)d_in[0];  // [128,3,256,256] f32
  const float* mean   = (const float*)d_in[1];  // [182] f32
  const int*   radius = (const int*)d_in[2];    // [256,129] i32
  float* out = (float*)d_out;                   // scalar f32

  float2* inter = (float2*)d_ws;                           // [B][WC][H] complex
  size_t inter_bytes = (size_t)B_ * WC_ * H_ * sizeof(float2);
  float* partial = (float*)((char*)d_ws + inter_bytes);    // [B][NG][L]
  float* cntpart = partial + (size_t)B_ * NG_ * L_;        // [NG][L]
  float* lpart   = cntpart + (size_t)NG_ * L_;             // [B]

  pass1_kernel<<<B_ * 16, 256, 0, stream>>>(data, (float4*)inter);
  pass2_kernel<<<B_ * NG_, 256, 0, stream>>>(inter, radius, partial, cntpart);
  loss_kernel<<<B_, 64, 0, stream>>>(partial, cntpart, mean, lpart);
  final_kernel<<<1, 64, 0, stream>>>(lpart, out);
}